// Round 1
// baseline (810.814 us; speedup 1.0000x reference)
//
#include <hip/hip_runtime.h>
#include <math.h>

#define N_NODES 50000
#define N_EDGES 600000
#define H 128
#define BN_EPS 1e-5f
// ordered-int encoding of -inf for atomicMax-on-float
#define NEG_INF_ENC 0x807FFFFF

__device__ __forceinline__ int enc_f(float v) {
    int b = __float_as_int(v);
    return b >= 0 ? b : (b ^ 0x7FFFFFFF);
}
__device__ __forceinline__ float dec_f(int e) {
    return e >= 0 ? __int_as_float(e) : __int_as_float(e ^ 0x7FFFFFFF);
}

// ---------------- K0: init workspace ----------------
__global__ void k_init(float* neigh, int* segmax, float* segsum, float* stats) {
    int stride = gridDim.x * blockDim.x;
    int i0 = blockIdx.x * blockDim.x + threadIdx.x;
    for (int i = i0; i < N_NODES * H; i += stride) neigh[i] = 0.0f;
    for (int i = i0; i < N_NODES; i += stride) {
        segsum[i] = 0.0f;
        segmax[i] = NEG_INF_ENC;
    }
    if (i0 < 256) stats[i0] = 0.0f;
}

// ---------------- K1: edge dot scores + segment max ----------------
// one wave (64 lanes) per edge; lane i handles features [2i, 2i+1]
__global__ void k_scores(const float* __restrict__ emb,
                         const int* __restrict__ src, const int* __restrict__ dst,
                         float* __restrict__ scores, int* __restrict__ segmax) {
    int wid = (blockIdx.x * blockDim.x + threadIdx.x) >> 6;
    int lane = threadIdx.x & 63;
    if (wid >= N_EDGES) return;
    int s = src[wid], d = dst[wid];
    const float2* ps = (const float2*)(emb + (size_t)s * H);
    const float2* pd = (const float2*)(emb + (size_t)d * H);
    float2 a = ps[lane];
    float2 b = pd[lane];
    float v = a.x * b.x + a.y * b.y;
#pragma unroll
    for (int off = 32; off > 0; off >>= 1) v += __shfl_xor(v, off, 64);
    if (lane == 0) {
        scores[wid] = v;
        atomicMax(segmax + d, enc_f(v));
    }
}

// ---------------- K2: e = exp(s - max) ; segment sum ----------------
__global__ void k_exp(const float* __restrict__ scores_in, float* __restrict__ evals,
                      const int* __restrict__ dst, const int* __restrict__ segmax,
                      float* __restrict__ segsum) {
    int e = blockIdx.x * blockDim.x + threadIdx.x;
    if (e >= N_EDGES) return;
    int d = dst[e];
    float m = dec_f(segmax[d]);
    float ev = expf(scores_in[e] - m);
    evals[e] = ev;
    atomicAdd(segsum + d, ev);
}

// ---------------- K3: weighted aggregation into neigh ----------------
// one wave per edge; lane i atomically adds 2 features
__global__ void k_agg(const float* __restrict__ emb, const float* __restrict__ evals,
                      const int* __restrict__ src, const int* __restrict__ dst,
                      const float* __restrict__ segsum, float* __restrict__ neigh) {
    int wid = (blockIdx.x * blockDim.x + threadIdx.x) >> 6;
    int lane = threadIdx.x & 63;
    if (wid >= N_EDGES) return;
    int s = src[wid], d = dst[wid];
    float norm = evals[wid] / segsum[d];
    const float2* ps = (const float2*)(emb + (size_t)s * H);
    float2 a = ps[lane];
    float* outp = neigh + (size_t)d * H + lane * 2;
    atomicAdd(outp, a.x * norm);
    atomicAdd(outp + 1, a.y * norm);
}

// ---------------- K4: in-place matmul neigh @ W (128x128) ----------------
// 32 rows per block, W staged in LDS in two 64-row halves, 4x4 reg blocking
#define MM_ROWS 32
#define LDP 129
__global__ __launch_bounds__(256) void k_matmul(float* __restrict__ neigh,
                                                const float* __restrict__ W) {
    __shared__ float Rl[MM_ROWS * LDP];  // 16.5 KB
    __shared__ float Wl[64 * LDP];       // 33 KB
    int t = threadIdx.x;
    int n0 = blockIdx.x * MM_ROWS;

    // load 32 rows into LDS (zeros past N)
    for (int idx = t; idx < MM_ROWS * H; idx += 256) {
        int r = idx >> 7, k = idx & 127;
        int n = n0 + r;
        Rl[r * LDP + k] = (n < N_NODES) ? neigh[(size_t)n * H + k] : 0.0f;
    }

    int cg = t & 31, rg = t >> 5;
    int j0 = cg * 4, r0 = rg * 4;
    float acc[4][4] = {};

    for (int half = 0; half < 2; ++half) {
        __syncthreads();
        for (int idx = t; idx < 64 * H; idx += 256) {
            int k = idx >> 7, j = idx & 127;
            Wl[k * LDP + j] = W[(size_t)(half * 64 + k) * H + j];
        }
        __syncthreads();
        int kbase = half * 64;
        for (int k = 0; k < 64; ++k) {
            float rv[4], wv[4];
#pragma unroll
            for (int i = 0; i < 4; ++i) rv[i] = Rl[(r0 + i) * LDP + kbase + k];
#pragma unroll
            for (int c = 0; c < 4; ++c) wv[c] = Wl[k * LDP + j0 + c];
#pragma unroll
            for (int i = 0; i < 4; ++i)
#pragma unroll
                for (int c = 0; c < 4; ++c) acc[i][c] += rv[i] * wv[c];
        }
    }

    // in-place store (all global row reads completed before first barrier pair)
#pragma unroll
    for (int i = 0; i < 4; ++i) {
        int n = n0 + r0 + i;
        if (n < N_NODES) {
#pragma unroll
            for (int c = 0; c < 4; ++c) neigh[(size_t)n * H + j0 + c] = acc[i][c];
        }
    }
}

// ---------------- K5: per-column sum / sumsq ----------------
__global__ void k_colreduce(const float* __restrict__ h, float* __restrict__ stats) {
    __shared__ float Sl[256], Ql[256];
    int t = threadIdx.x;
    int j = t & 127;
    float s = 0.0f, q = 0.0f;
    for (int r = blockIdx.x * 2 + (t >> 7); r < N_NODES; r += gridDim.x * 2) {
        float v = h[(size_t)r * H + j];
        s += v;
        q += v * v;
    }
    Sl[t] = s; Ql[t] = q;
    __syncthreads();
    if (t < 128) {
        atomicAdd(stats + j, Sl[t] + Sl[t + 128]);
        atomicAdd(stats + 128 + j, Ql[t] + Ql[t + 128]);
    }
}

// ---------------- K6: finalize BN scale/shift ----------------
__global__ void k_finalize(const float* __restrict__ stats, const float* __restrict__ gamma,
                           const float* __restrict__ beta, float* __restrict__ ss) {
    int j = threadIdx.x;
    float mean = stats[j] * (1.0f / N_NODES);
    float var = stats[128 + j] * (1.0f / N_NODES) - mean * mean;
    var = fmaxf(var, 0.0f);
    float sc = gamma[j] * rsqrtf(var + BN_EPS);
    ss[j] = sc;
    ss[128 + j] = beta[j] - mean * sc;
}

// ---------------- K7: apply BN + tanh ----------------
__global__ void k_apply(const float* __restrict__ h, const float* __restrict__ ss,
                        float* __restrict__ out) {
    int stride = gridDim.x * blockDim.x;
    for (int i = blockIdx.x * blockDim.x + threadIdx.x; i < N_NODES * H; i += stride) {
        int j = i & 127;
        out[i] = tanhf(h[i] * ss[j] + ss[128 + j]);
    }
}

extern "C" void kernel_launch(void* const* d_in, const int* in_sizes, int n_in,
                              void* d_out, int out_size, void* d_ws, size_t ws_size,
                              hipStream_t stream) {
    const float* emb   = (const float*)d_in[0];
    const float* W     = (const float*)d_in[1];
    const float* gamma = (const float*)d_in[2];
    const float* beta  = (const float*)d_in[3];
    const int*   src   = (const int*)d_in[4];
    const int*   dst   = (const int*)d_in[5];
    float* out = (float*)d_out;

    float* ws = (float*)d_ws;
    float* scores = ws;                                   // E floats
    int*   segmax = (int*)(ws + N_EDGES);                 // N ints
    float* segsum = ws + N_EDGES + N_NODES;               // N floats
    float* neigh  = segsum + N_NODES;                     // N*H floats (reused as h)
    float* stats  = neigh + (size_t)N_NODES * H;          // 256 floats
    float* ss     = stats + 256;                          // 256 floats

    k_init<<<2048, 256, 0, stream>>>(neigh, segmax, segsum, stats);
    k_scores<<<(N_EDGES + 3) / 4, 256, 0, stream>>>(emb, src, dst, scores, segmax);
    k_exp<<<(N_EDGES + 255) / 256, 256, 0, stream>>>(scores, scores, dst, segmax, segsum);
    k_agg<<<(N_EDGES + 3) / 4, 256, 0, stream>>>(emb, scores, src, dst, segsum, neigh);
    k_matmul<<<(N_NODES + MM_ROWS - 1) / MM_ROWS, 256, 0, stream>>>(neigh, W);
    k_colreduce<<<512, 256, 0, stream>>>(neigh, stats);
    k_finalize<<<1, 128, 0, stream>>>(stats, gamma, beta, ss);
    k_apply<<<4096, 256, 0, stream>>>(neigh, ss, out);
}

// Round 3
// 392.237 us; speedup vs baseline: 2.0672x; 2.0672x over previous
//
#include <hip/hip_runtime.h>
#include <math.h>

#define N_NODES 50000
#define N_EDGES 600000
#define H 128
#define BN_EPS 1e-5f
#define NSCAN_BLOCKS ((N_NODES + 255) / 256)   // 196

// ---------------- K0: zero counters + stats ----------------
__global__ void k_init(int* __restrict__ cnt, float* __restrict__ stats) {
    int i = blockIdx.x * blockDim.x + threadIdx.x;
    int stride = gridDim.x * blockDim.x;
    for (int j = i; j < N_NODES; j += stride) cnt[j] = 0;
    if (i < 256) stats[i] = 0.0f;
}

// ---------------- K1: in-degree histogram ----------------
__global__ void k_hist(const int* __restrict__ dst, int* __restrict__ cnt) {
    int i = blockIdx.x * blockDim.x + threadIdx.x;
    if (i < N_EDGES) atomicAdd(cnt + dst[i], 1);
}

// ---------------- K2a: per-block inclusive scan (256 elems/block) ----------------
__global__ void k_scan1(const int* __restrict__ cnt, int* __restrict__ incl,
                        int* __restrict__ bsum) {
    __shared__ int sm[256];
    int t = threadIdx.x;
    int i = blockIdx.x * 256 + t;
    sm[t] = (i < N_NODES) ? cnt[i] : 0;
    __syncthreads();
    for (int off = 1; off < 256; off <<= 1) {
        int add = (t >= off) ? sm[t - off] : 0;
        __syncthreads();
        sm[t] += add;
        __syncthreads();
    }
    if (i < N_NODES) incl[i] = sm[t];
    if (t == 255) bsum[blockIdx.x] = sm[255];
}

// ---------------- K2b: scan block sums, produce exclusive offsets + cursor ----------------
__global__ void k_scan2(const int* __restrict__ incl, const int* __restrict__ cnt,
                        const int* __restrict__ bsum, int* __restrict__ row_off,
                        int* __restrict__ cursor) {
    __shared__ int boff[NSCAN_BLOCKS];
    int t = threadIdx.x;
    if (t == 0) {
        int run = 0;
        for (int b = 0; b < NSCAN_BLOCKS; ++b) { boff[b] = run; run += bsum[b]; }
    }
    __syncthreads();
    for (int i = t; i < N_NODES; i += blockDim.x) {
        int e = incl[i] + boff[i >> 8] - cnt[i];  // exclusive global offset
        row_off[i] = e;
        cursor[i] = e;
    }
}

// ---------------- K3: scatter src ids into dst-sorted (CSR) order ----------------
__global__ void k_scatter(const int* __restrict__ src, const int* __restrict__ dst,
                          int* __restrict__ cursor, int* __restrict__ srcs_sorted) {
    int i = blockIdx.x * blockDim.x + threadIdx.x;
    if (i < N_EDGES) {
        int pos = atomicAdd(cursor + dst[i], 1);
        srcs_sorted[pos] = src[i];
    }
}

// ---------------- K4: fused score + ONLINE softmax + weighted aggregation ----------------
// one wave per dst node; lane i owns features [2i, 2i+1].
// Online softmax (running max m, rescale by exp(m_old-m_new)) is required:
// self-loop edges (src==dst, ~12 of them) have score = |e|^2 ~ 128 and
// exp(128) overflows fp32 -> NaN without the max shift.
// NOTE: sc[q] is broadcast across all 64 lanes after the butterfly, so ssum
// is already the full sum in every lane — no final cross-lane reduce.
__global__ __launch_bounds__(256) void k_fused(const float* __restrict__ emb,
                                               const int* __restrict__ row_off,
                                               const int* __restrict__ cursor,
                                               const int* __restrict__ srcs,
                                               float* __restrict__ neigh) {
    int wid = (blockIdx.x * blockDim.x + threadIdx.x) >> 6;
    int lane = threadIdx.x & 63;
    if (wid >= N_NODES) return;
    int base = row_off[wid];
    int deg = cursor[wid] - base;   // cursor ends at inclusive offset after scatter

    const float2* pd = (const float2*)(emb + (size_t)wid * H);
    float2 b = pd[lane];

    float m = -INFINITY;
    float ssum = 0.0f;
    float2 acc = make_float2(0.0f, 0.0f);

    for (int cb = 0; cb < deg; cb += 8) {
        int cl = min(8, deg - cb);
        float2 a[8];
        float sc[8];
#pragma unroll
        for (int q = 0; q < 8; ++q) {
            if (q < cl) {
                int s = srcs[base + cb + q];
                a[q] = ((const float2*)(emb + (size_t)s * H))[lane];
            }
        }
        float cmax = -INFINITY;
#pragma unroll
        for (int q = 0; q < 8; ++q) {
            if (q < cl) {
                float v = a[q].x * b.x + a[q].y * b.y;
#pragma unroll
                for (int off = 32; off > 0; off >>= 1) v += __shfl_xor(v, off, 64);
                sc[q] = v;
                cmax = fmaxf(cmax, v);
            }
        }
        float mnew = fmaxf(m, cmax);
        float scale = __expf(m - mnew);   // first chunk: exp(-inf)=0
        ssum *= scale;
        acc.x *= scale;
        acc.y *= scale;
        m = mnew;
#pragma unroll
        for (int q = 0; q < 8; ++q) {
            if (q < cl) {
                float ev = __expf(sc[q] - m);
                ssum += ev;
                acc.x += ev * a[q].x;
                acc.y += ev * a[q].y;
            }
        }
    }
    float inv = (deg > 0) ? 1.0f / ssum : 0.0f;
    float2* po = (float2*)(neigh + (size_t)wid * H);
    po[lane] = make_float2(acc.x * inv, acc.y * inv);
}

// ---------------- K5: in-place matmul neigh @ W (128x128) ----------------
#define MM_ROWS 32
#define LDP 129
__global__ __launch_bounds__(256) void k_matmul(float* __restrict__ neigh,
                                                const float* __restrict__ W) {
    __shared__ float Rl[MM_ROWS * LDP];
    __shared__ float Wl[64 * LDP];
    int t = threadIdx.x;
    int n0 = blockIdx.x * MM_ROWS;

    for (int idx = t; idx < MM_ROWS * H; idx += 256) {
        int r = idx >> 7, k = idx & 127;
        int n = n0 + r;
        Rl[r * LDP + k] = (n < N_NODES) ? neigh[(size_t)n * H + k] : 0.0f;
    }

    int cg = t & 31, rg = t >> 5;
    int j0 = cg * 4, r0 = rg * 4;
    float acc[4][4] = {};

    for (int half = 0; half < 2; ++half) {
        __syncthreads();
        for (int idx = t; idx < 64 * H; idx += 256) {
            int k = idx >> 7, j = idx & 127;
            Wl[k * LDP + j] = W[(size_t)(half * 64 + k) * H + j];
        }
        __syncthreads();
        int kbase = half * 64;
        for (int k = 0; k < 64; ++k) {
            float rv[4], wv[4];
#pragma unroll
            for (int i = 0; i < 4; ++i) rv[i] = Rl[(r0 + i) * LDP + kbase + k];
#pragma unroll
            for (int c = 0; c < 4; ++c) wv[c] = Wl[k * LDP + j0 + c];
#pragma unroll
            for (int i = 0; i < 4; ++i)
#pragma unroll
                for (int c = 0; c < 4; ++c) acc[i][c] += rv[i] * wv[c];
        }
    }

#pragma unroll
    for (int i = 0; i < 4; ++i) {
        int n = n0 + r0 + i;
        if (n < N_NODES) {
#pragma unroll
            for (int c = 0; c < 4; ++c) neigh[(size_t)n * H + j0 + c] = acc[i][c];
        }
    }
}

// ---------------- K6: per-column sum / sumsq ----------------
__global__ void k_colreduce(const float* __restrict__ h, float* __restrict__ stats) {
    __shared__ float Sl[256], Ql[256];
    int t = threadIdx.x;
    int j = t & 127;
    float s = 0.0f, q = 0.0f;
    for (int r = blockIdx.x * 2 + (t >> 7); r < N_NODES; r += gridDim.x * 2) {
        float v = h[(size_t)r * H + j];
        s += v;
        q += v * v;
    }
    Sl[t] = s; Ql[t] = q;
    __syncthreads();
    if (t < 128) {
        atomicAdd(stats + j, Sl[t] + Sl[t + 128]);
        atomicAdd(stats + 128 + j, Ql[t] + Ql[t + 128]);
    }
}

// ---------------- K7: finalize BN scale/shift ----------------
__global__ void k_finalize(const float* __restrict__ stats, const float* __restrict__ gamma,
                           const float* __restrict__ beta, float* __restrict__ ss) {
    int j = threadIdx.x;
    float mean = stats[j] * (1.0f / N_NODES);
    float var = stats[128 + j] * (1.0f / N_NODES) - mean * mean;
    var = fmaxf(var, 0.0f);
    float sc = gamma[j] * rsqrtf(var + BN_EPS);
    ss[j] = sc;
    ss[128 + j] = beta[j] - mean * sc;
}

// ---------------- K8: apply BN + tanh ----------------
__global__ void k_apply(const float* __restrict__ h, const float* __restrict__ ss,
                        float* __restrict__ out) {
    int stride = gridDim.x * blockDim.x;
    for (int i = blockIdx.x * blockDim.x + threadIdx.x; i < N_NODES * H; i += stride) {
        int j = i & 127;
        out[i] = tanhf(h[i] * ss[j] + ss[128 + j]);
    }
}

extern "C" void kernel_launch(void* const* d_in, const int* in_sizes, int n_in,
                              void* d_out, int out_size, void* d_ws, size_t ws_size,
                              hipStream_t stream) {
    const float* emb   = (const float*)d_in[0];
    const float* W     = (const float*)d_in[1];
    const float* gamma = (const float*)d_in[2];
    const float* beta  = (const float*)d_in[3];
    const int*   src   = (const int*)d_in[4];
    const int*   dst   = (const int*)d_in[5];
    float* out = (float*)d_out;

    int* wsi = (int*)d_ws;
    int* cnt         = wsi;                       // N
    int* incl        = cnt + N_NODES;             // N
    int* bsum        = incl + N_NODES;            // 256 (196 used)
    int* row_off     = bsum + 256;                // N
    int* cursor      = row_off + N_NODES;         // N
    int* srcs_sorted = cursor + N_NODES;          // E
    float* neigh     = (float*)(srcs_sorted + N_EDGES);   // N*H (reused as h)
    float* stats     = neigh + (size_t)N_NODES * H;       // 256
    float* ss        = stats + 256;                       // 256

    k_init<<<NSCAN_BLOCKS, 256, 0, stream>>>(cnt, stats);
    k_hist<<<(N_EDGES + 255) / 256, 256, 0, stream>>>(dst, cnt);
    k_scan1<<<NSCAN_BLOCKS, 256, 0, stream>>>(cnt, incl, bsum);
    k_scan2<<<1, 256, 0, stream>>>(incl, cnt, bsum, row_off, cursor);
    k_scatter<<<(N_EDGES + 255) / 256, 256, 0, stream>>>(src, dst, cursor, srcs_sorted);
    k_fused<<<(N_NODES * 64 + 255) / 256, 256, 0, stream>>>(emb, row_off, cursor, srcs_sorted, neigh);
    k_matmul<<<(N_NODES + MM_ROWS - 1) / MM_ROWS, 256, 0, stream>>>(neigh, W);
    k_colreduce<<<512, 256, 0, stream>>>(neigh, stats);
    k_finalize<<<1, 128, 0, stream>>>(stats, gamma, beta, ss);
    k_apply<<<4096, 256, 0, stream>>>(neigh, ss, out);
}

// Round 4
// 270.397 us; speedup vs baseline: 2.9986x; 1.4506x over previous
//
#include <hip/hip_runtime.h>
#include <math.h>

#define N_NODES 50000
#define N_EDGES 600000
#define H 128
#define BN_EPS 1e-5f
#define NSCAN_BLOCKS ((N_NODES + 255) / 256)   // 196

// ---------------- K0: zero counters + stats ----------------
__global__ void k_init(int* __restrict__ cnt, float* __restrict__ stats) {
    int i = blockIdx.x * blockDim.x + threadIdx.x;
    int stride = gridDim.x * blockDim.x;
    for (int j = i; j < N_NODES; j += stride) cnt[j] = 0;
    if (i < 256) stats[i] = 0.0f;
}

// ---------------- K1: in-degree histogram ----------------
__global__ void k_hist(const int* __restrict__ dst, int* __restrict__ cnt) {
    int i = blockIdx.x * blockDim.x + threadIdx.x;
    if (i < N_EDGES) atomicAdd(cnt + dst[i], 1);
}

// ---------------- K2a: per-block inclusive scan (256 elems/block) ----------------
__global__ void k_scan1(const int* __restrict__ cnt, int* __restrict__ incl,
                        int* __restrict__ bsum) {
    __shared__ int sm[256];
    int t = threadIdx.x;
    int i = blockIdx.x * 256 + t;
    sm[t] = (i < N_NODES) ? cnt[i] : 0;
    __syncthreads();
    for (int off = 1; off < 256; off <<= 1) {
        int add = (t >= off) ? sm[t - off] : 0;
        __syncthreads();
        sm[t] += add;
        __syncthreads();
    }
    if (i < N_NODES) incl[i] = sm[t];
    if (t == 255) bsum[blockIdx.x] = sm[255];
}

// ---------------- K2b: PARALLEL block-sum scan + offsets ----------------
// every block redundantly scans the 196 block sums in LDS (8 steps), then
// writes its own 256 nodes' offsets. Replaces the serial thread-0 loop that
// was ~196 dependent global loads (~40 us latency-bound).
__global__ void k_scan2(const int* __restrict__ incl, const int* __restrict__ cnt,
                        const int* __restrict__ bsum, int* __restrict__ row_off,
                        int* __restrict__ cursor) {
    __shared__ int sm[256];
    int t = threadIdx.x;
    sm[t] = (t < NSCAN_BLOCKS) ? bsum[t] : 0;
    __syncthreads();
    for (int off = 1; off < 256; off <<= 1) {
        int add = (t >= off) ? sm[t - off] : 0;
        __syncthreads();
        sm[t] += add;
        __syncthreads();
    }
    int boff = (blockIdx.x == 0) ? 0 : sm[blockIdx.x - 1];
    int i = blockIdx.x * 256 + t;
    if (i < N_NODES) {
        int e = incl[i] + boff - cnt[i];  // exclusive global offset
        row_off[i] = e;
        cursor[i] = e;
    }
}

// ---------------- K3: scatter src ids into dst-sorted (CSR) order ----------------
__global__ void k_scatter(const int* __restrict__ src, const int* __restrict__ dst,
                          int* __restrict__ cursor, int* __restrict__ srcs_sorted) {
    int i = blockIdx.x * blockDim.x + threadIdx.x;
    if (i < N_EDGES) {
        int pos = atomicAdd(cursor + dst[i], 1);
        srcs_sorted[pos] = src[i];
    }
}

#define F4SCALE(a, s) { (a).x *= (s); (a).y *= (s); (a).z *= (s); (a).w *= (s); }
#define F4FMA(a, e, v) { (a).x += (e)*(v).x; (a).y += (e)*(v).y; (a).z += (e)*(v).z; (a).w += (e)*(v).w; }
#define F4SHFLADD(a, msk) { (a).x += __shfl_xor((a).x, msk, 64); (a).y += __shfl_xor((a).y, msk, 64); \
                            (a).z += __shfl_xor((a).z, msk, 64); (a).w += __shfl_xor((a).w, msk, 64); }

// ---------------- K4: fused score + online softmax + aggregation ----------------
// one wave per dst node. Wave split into 8 groups x 8 lanes; group g handles
// edge (chunk_base+g), lane (l = lane&7) owns features [16l,16l+16) as 4xfloat4.
// Dot-product reduce = 3 shfl within the group (vs 6 wave-wide per edge before).
// Online softmax (running max) required: self-loop edges score ~|e|^2 ~ 128,
// exp(128) overflows fp32.
__global__ __launch_bounds__(256) void k_fused(const float* __restrict__ emb,
                                               const int* __restrict__ row_off,
                                               const int* __restrict__ row_end,
                                               const int* __restrict__ srcs,
                                               float* __restrict__ neigh) {
    int wid = (blockIdx.x * blockDim.x + threadIdx.x) >> 6;
    int lane = threadIdx.x & 63;
    if (wid >= N_NODES) return;
    int g = lane >> 3;   // edge slot within chunk
    int l = lane & 7;    // feature slice

    int base = row_off[wid];
    int deg = row_end[wid] - base;

    const float4* rd = (const float4*)(emb + (size_t)wid * H) + l * 4;
    float4 b0 = rd[0], b1 = rd[1], b2 = rd[2], b3 = rd[3];

    float m = -INFINITY, ssum = 0.0f;
    float4 acc0 = {0,0,0,0}, acc1 = {0,0,0,0}, acc2 = {0,0,0,0}, acc3 = {0,0,0,0};

    for (int cb = 0; cb < deg; cb += 8) {
        int e = cb + g;
        bool valid = e < deg;
        int s = srcs[base + (valid ? e : 0)];
        const float4* rs = (const float4*)(emb + (size_t)s * H) + l * 4;
        float4 a0 = rs[0], a1 = rs[1], a2 = rs[2], a3 = rs[3];

        float v = a0.x*b0.x + a0.y*b0.y + a0.z*b0.z + a0.w*b0.w
                + a1.x*b1.x + a1.y*b1.y + a1.z*b1.z + a1.w*b1.w
                + a2.x*b2.x + a2.y*b2.y + a2.z*b2.z + a2.w*b2.w
                + a3.x*b3.x + a3.y*b3.y + a3.z*b3.z + a3.w*b3.w;
        v += __shfl_xor(v, 1, 64);
        v += __shfl_xor(v, 2, 64);
        v += __shfl_xor(v, 4, 64);
        if (!valid) v = -INFINITY;

        float cmax = v;
        cmax = fmaxf(cmax, __shfl_xor(cmax, 8, 64));
        cmax = fmaxf(cmax, __shfl_xor(cmax, 16, 64));
        cmax = fmaxf(cmax, __shfl_xor(cmax, 32, 64));
        float mnew = fmaxf(m, cmax);          // finite: slot 0 always valid
        float scale = __expf(m - mnew);       // first chunk: exp(-inf)=0
        ssum *= scale;
        F4SCALE(acc0, scale); F4SCALE(acc1, scale);
        F4SCALE(acc2, scale); F4SCALE(acc3, scale);
        m = mnew;

        float ev = __expf(v - m);             // invalid: exp(-inf)=0
        ssum += ev;
        F4FMA(acc0, ev, a0); F4FMA(acc1, ev, a1);
        F4FMA(acc2, ev, a2); F4FMA(acc3, ev, a3);
    }

    // reduce across the 8 groups (each lane ends with full sums for its slice)
    ssum += __shfl_xor(ssum, 8, 64);
    ssum += __shfl_xor(ssum, 16, 64);
    ssum += __shfl_xor(ssum, 32, 64);
    F4SHFLADD(acc0, 8);  F4SHFLADD(acc1, 8);  F4SHFLADD(acc2, 8);  F4SHFLADD(acc3, 8);
    F4SHFLADD(acc0, 16); F4SHFLADD(acc1, 16); F4SHFLADD(acc2, 16); F4SHFLADD(acc3, 16);
    F4SHFLADD(acc0, 32); F4SHFLADD(acc1, 32); F4SHFLADD(acc2, 32); F4SHFLADD(acc3, 32);

    float inv = (deg > 0) ? 1.0f / ssum : 0.0f;
    if (g == 0) {
        float4* po = (float4*)(neigh + (size_t)wid * H) + l * 4;
        F4SCALE(acc0, inv); F4SCALE(acc1, inv); F4SCALE(acc2, inv); F4SCALE(acc3, inv);
        po[0] = acc0; po[1] = acc1; po[2] = acc2; po[3] = acc3;
    }
}

// ---------------- K5: in-place matmul neigh @ W + fused BN column stats ----------------
#define MM_ROWS 32
#define LDP 129   // Rl padding (scalar broadcast reads, conflict-free)
#define LDW 132   // Wl padding: multiple of 4 floats -> aligned ds_read_b128
__global__ __launch_bounds__(256) void k_matmul(float* __restrict__ neigh,
                                                const float* __restrict__ W,
                                                float* __restrict__ stats) {
    __shared__ float Rl[MM_ROWS * LDP];
    __shared__ float Wl[64 * LDW];   // 33.8 KB, reused for stats reduction
    int t = threadIdx.x;
    int n0 = blockIdx.x * MM_ROWS;

    for (int idx = t; idx < MM_ROWS * H; idx += 256) {
        int r = idx >> 7, k = idx & 127;
        int n = n0 + r;
        Rl[r * LDP + k] = (n < N_NODES) ? neigh[(size_t)n * H + k] : 0.0f;
    }

    int cg = t & 31, rg = t >> 5;
    int j0 = cg * 4, r0 = rg * 4;
    float acc[4][4] = {};

    for (int half = 0; half < 2; ++half) {
        __syncthreads();
        // stage 64 rows of W as float4s
        for (int idx = t; idx < 64 * 32; idx += 256) {
            int k = idx >> 5, c4 = idx & 31;
            float4 w = ((const float4*)(W + (size_t)(half * 64 + k) * H))[c4];
            *(float4*)&Wl[k * LDW + c4 * 4] = w;
        }
        __syncthreads();
        int kbase = half * 64;
        for (int k = 0; k < 64; ++k) {
            float rv[4];
#pragma unroll
            for (int i = 0; i < 4; ++i) rv[i] = Rl[(r0 + i) * LDP + kbase + k];
            float4 wv = *(const float4*)&Wl[k * LDW + j0];
#pragma unroll
            for (int i = 0; i < 4; ++i) {
                acc[i][0] += rv[i] * wv.x;
                acc[i][1] += rv[i] * wv.y;
                acc[i][2] += rv[i] * wv.z;
                acc[i][3] += rv[i] * wv.w;
            }
        }
    }

    // store C (rows past N are zero-padded in Rl; skip their stores)
#pragma unroll
    for (int i = 0; i < 4; ++i) {
        int n = n0 + r0 + i;
        if (n < N_NODES) {
#pragma unroll
            for (int c = 0; c < 4; ++c) neigh[(size_t)n * H + j0 + c] = acc[i][c];
        }
    }

    // fused BN column stats: per-thread 4-col partials -> LDS -> 1 atomic/col
    float s4[4], q4[4];
#pragma unroll
    for (int c = 0; c < 4; ++c) {
        float s = 0.0f, q = 0.0f;
#pragma unroll
        for (int i = 0; i < 4; ++i) { s += acc[i][c]; q += acc[i][c] * acc[i][c]; }
        s4[c] = s; q4[c] = q;
    }
    __syncthreads();  // done reading Wl; reuse as Sl/Ql
    float* Sl = Wl;
    float* Ql = Wl + 1024;
#pragma unroll
    for (int c = 0; c < 4; ++c) {
        Sl[rg * 128 + j0 + c] = s4[c];
        Ql[rg * 128 + j0 + c] = q4[c];
    }
    __syncthreads();
    if (t < 128) {
        float s = 0.0f;
#pragma unroll
        for (int r = 0; r < 8; ++r) s += Sl[r * 128 + t];
        atomicAdd(stats + t, s);
    } else {
        int j = t - 128;
        float q = 0.0f;
#pragma unroll
        for (int r = 0; r < 8; ++r) q += Ql[r * 128 + j];
        atomicAdd(stats + 128 + j, q);
    }
}

// ---------------- K6: finalize BN scale/shift ----------------
__global__ void k_finalize(const float* __restrict__ stats, const float* __restrict__ gamma,
                           const float* __restrict__ beta, float* __restrict__ ss) {
    int j = threadIdx.x;
    float mean = stats[j] * (1.0f / N_NODES);
    float var = stats[128 + j] * (1.0f / N_NODES) - mean * mean;
    var = fmaxf(var, 0.0f);
    float sc = gamma[j] * rsqrtf(var + BN_EPS);
    ss[j] = sc;
    ss[128 + j] = beta[j] - mean * sc;
}

// ---------------- K7: apply BN + tanh ----------------
__global__ void k_apply(const float* __restrict__ h, const float* __restrict__ ss,
                        float* __restrict__ out) {
    int stride = gridDim.x * blockDim.x;
    for (int i = blockIdx.x * blockDim.x + threadIdx.x; i < N_NODES * H; i += stride) {
        int j = i & 127;
        out[i] = tanhf(h[i] * ss[j] + ss[128 + j]);
    }
}

extern "C" void kernel_launch(void* const* d_in, const int* in_sizes, int n_in,
                              void* d_out, int out_size, void* d_ws, size_t ws_size,
                              hipStream_t stream) {
    const float* emb   = (const float*)d_in[0];
    const float* W     = (const float*)d_in[1];
    const float* gamma = (const float*)d_in[2];
    const float* beta  = (const float*)d_in[3];
    const int*   src   = (const int*)d_in[4];
    const int*   dst   = (const int*)d_in[5];
    float* out = (float*)d_out;

    int* wsi = (int*)d_ws;
    int* cnt         = wsi;                       // N
    int* incl        = cnt + N_NODES;             // N
    int* bsum        = incl + N_NODES;            // 256 (196 used)
    int* row_off     = bsum + 256;                // N
    int* cursor      = row_off + N_NODES;         // N
    int* srcs_sorted = cursor + N_NODES;          // E
    float* neigh     = (float*)(srcs_sorted + N_EDGES);   // N*H (reused as h)
    float* stats     = neigh + (size_t)N_NODES * H;       // 256
    float* ss        = stats + 256;                       // 256

    k_init<<<NSCAN_BLOCKS, 256, 0, stream>>>(cnt, stats);
    k_hist<<<(N_EDGES + 255) / 256, 256, 0, stream>>>(dst, cnt);
    k_scan1<<<NSCAN_BLOCKS, 256, 0, stream>>>(cnt, incl, bsum);
    k_scan2<<<NSCAN_BLOCKS, 256, 0, stream>>>(incl, cnt, bsum, row_off, cursor);
    k_scatter<<<(N_EDGES + 255) / 256, 256, 0, stream>>>(src, dst, cursor, srcs_sorted);
    k_fused<<<(N_NODES * 64 + 255) / 256, 256, 0, stream>>>(emb, row_off, cursor, srcs_sorted, neigh);
    k_matmul<<<(N_NODES + MM_ROWS - 1) / MM_ROWS, 256, 0, stream>>>(neigh, W, stats);
    k_finalize<<<1, 128, 0, stream>>>(stats, gamma, beta, ss);
    k_apply<<<4096, 256, 0, stream>>>(neigh, ss, out);
}